// Round 5
// baseline (1307.013 us; speedup 1.0000x reference)
//
#include <hip/hip_runtime.h>
#include <cstdint>

#define TTOK 8192
#define HID  1024
#define FFD  4096
#define NEXP 8
#define NASSIGN 16384   // TTOK * 2

typedef __attribute__((ext_vector_type(8))) short bf16x8;
typedef __attribute__((ext_vector_type(4))) float f32x4;

__device__ __forceinline__ unsigned short f2bf(float f) {
  unsigned int u = __builtin_bit_cast(unsigned int, f);
  u += 0x7FFFu + ((u >> 16) & 1u);           // RNE
  return (unsigned short)(u >> 16);
}

__device__ __forceinline__ void gload16(const unsigned short* g, unsigned short* l) {
  __builtin_amdgcn_global_load_lds(
      (const __attribute__((address_space(1))) unsigned int*)g,
      (__attribute__((address_space(3))) unsigned int*)l, 16, 0, 0);
}

// ---------------- routing ----------------

__global__ void zero_counts_kernel(int* counts) {
  if (threadIdx.x < NEXP) counts[threadIdx.x] = 0;
}

__global__ void gate_kernel(const float* __restrict__ x,
                            const float* __restrict__ gw,
                            const float* __restrict__ gb,
                            float* __restrict__ logits_out,
                            int* __restrict__ counts,
                            int* __restrict__ te, int* __restrict__ tp,
                            float* __restrict__ tw) {
  const int lane = threadIdx.x & 63;
  const int wib  = threadIdx.x >> 6;
  const int t = blockIdx.x * 4 + wib;
  const float* xr = x + (size_t)t * HID;

  float acc[NEXP];
#pragma unroll
  for (int e = 0; e < NEXP; ++e) acc[e] = 0.f;

#pragma unroll
  for (int i = 0; i < HID / 64; ++i) {
    int h = lane + 64 * i;
    float xv = xr[h];
    const float* g = gw + h * NEXP;
#pragma unroll
    for (int e = 0; e < NEXP; ++e) acc[e] += xv * g[e];
  }
#pragma unroll
  for (int off = 32; off; off >>= 1)
#pragma unroll
    for (int e = 0; e < NEXP; ++e) acc[e] += __shfl_xor(acc[e], off);
#pragma unroll
  for (int e = 0; e < NEXP; ++e) acc[e] += gb[e];

  if (lane < NEXP) logits_out[(size_t)t * NEXP + lane] = acc[lane];

  if (lane == 0) {
    int e0 = 0; float v0 = acc[0];
#pragma unroll
    for (int e = 1; e < NEXP; ++e) if (acc[e] > v0) { v0 = acc[e]; e0 = e; }
    int e1 = -1; float v1 = -3.4e38f;
#pragma unroll
    for (int e = 0; e < NEXP; ++e) if (e != e0 && acc[e] > v1) { v1 = acc[e]; e1 = e; }
    float s = __expf(v1 - v0);         // v1 <= v0
    float w0 = 1.f / (1.f + s);
    float w1 = s * w0;
    int p0 = atomicAdd(&counts[e0], 1);
    int p1 = atomicAdd(&counts[e1], 1);
    te[t * 2] = e0; te[t * 2 + 1] = e1;
    tp[t * 2] = p0; tp[t * 2 + 1] = p1;
    tw[t * 2] = w0; tw[t * 2 + 1] = w1;
  }
}

__global__ void scatter_kernel(const int* __restrict__ counts, int* __restrict__ offsets,
                               const int* __restrict__ te, const int* __restrict__ tp,
                               const float* __restrict__ tw,
                               int* __restrict__ tok_of, float* __restrict__ wt_of,
                               int* __restrict__ asn_of) {
  __shared__ int offs[NEXP];
  if (threadIdx.x == 0) {
    int run = 0;
    for (int e = 0; e < NEXP; ++e) { offs[e] = run; offsets[e] = run; run += counts[e]; }
  }
  __syncthreads();
  for (int t = threadIdx.x; t < TTOK; t += blockDim.x) {
#pragma unroll
    for (int j = 0; j < 2; ++j) {
      int e = te[t * 2 + j];
      int a = offs[e] + tp[t * 2 + j];
      tok_of[a] = t;
      wt_of[a] = tw[t * 2 + j];
      asn_of[t * 2 + j] = a;
    }
  }
}

// ---------------- dtype prep ----------------

__global__ void convert_x_kernel(const float* __restrict__ x, unsigned short* __restrict__ xb) {
  size_t i = ((size_t)blockIdx.x * 256 + threadIdx.x) * 8;
  float4 a = *(const float4*)(x + i);
  float4 b = *(const float4*)(x + i + 4);
  union { unsigned short us[8]; uint4 v; } u;
  u.us[0] = f2bf(a.x); u.us[1] = f2bf(a.y); u.us[2] = f2bf(a.z); u.us[3] = f2bf(a.w);
  u.us[4] = f2bf(b.x); u.us[5] = f2bf(b.y); u.us[6] = f2bf(b.z); u.us[7] = f2bf(b.w);
  *(uint4*)(xb + i) = u.v;
}

// src [z][R][C] fp32 -> dst [z][C][R] bf16
__global__ void transpose_cvt_kernel(const float* __restrict__ src,
                                     unsigned short* __restrict__ dst, int R, int C) {
  __shared__ float tile[32][33];
  const int r0 = blockIdx.y * 32, c0 = blockIdx.x * 32;
  const size_t base = (size_t)blockIdx.z * R * C;
  src += base; dst += base;
#pragma unroll
  for (int i = threadIdx.y; i < 32; i += 8)
    tile[i][threadIdx.x] = src[(size_t)(r0 + i) * C + c0 + threadIdx.x];
  __syncthreads();
#pragma unroll
  for (int i = threadIdx.y; i < 32; i += 8)
    dst[(size_t)(c0 + i) * R + r0 + threadIdx.x] = f2bf(tile[threadIdx.x][i]);
}

// ---------------- expert GEMMs: 256-tile 8-phase template (m201 port) ----
// K-tile BK=64. Per iteration: stage ALL of kt+1 (8 gloads), vmcnt(8)
// (counted, never drains in loop), barrier, then 4 phases of
// {ds_read frags; barrier; lgkmcnt(0); setprio(1); 16 MFMA; setprio(0);
//  barrier}. LDS slot-swizzle: global col = (slot ^ (row&7))*8 staged
// linearly; read XORs the same term (per-lane constant).
// e = blockIdx.x & 7 pins expert e to XCD e (weight panels stay in one L2).

#define BK 64

// ---- up: BM=256 assignment rows x BN=128 f-cols, g and u fused ----
#define UBM 256
#define UBN 128

__global__ __launch_bounds__(512, 1) void moe_up_kernel(
    const unsigned short* __restrict__ xb,    // [T][H] bf16
    const unsigned short* __restrict__ WgT,   // [E][F][H] bf16
    const unsigned short* __restrict__ WuT,   // [E][F][H] bf16
    const int* __restrict__ counts, const int* __restrict__ offsets,
    const int* __restrict__ tok_of,
    unsigned short* __restrict__ hbuf)        // [A][F] bf16
{
  const int e = blockIdx.x & 7;               // expert <-> XCD affinity
  const int mblk = blockIdx.x >> 3;
  const int cnt = counts[e];
  if (mblk * UBM >= cnt) return;
  const int off = offsets[e];
  const int n0 = blockIdx.y * UBN;

  __shared__ __align__(16) unsigned short As[2][UBM * BK];    // 64 KiB
  __shared__ __align__(16) unsigned short Bgs[2][UBN * BK];   // 32 KiB
  __shared__ __align__(16) unsigned short Bus[2][UBN * BK];   // 32 KiB
  __shared__ int toks[UBM];

  const int tid = threadIdx.x;
  const int lane = tid & 63;
  const int w = tid >> 6;

  for (int i = tid; i < UBM; i += 512) {
    int a = off + mblk * UBM + i;
    if (a > NASSIGN - 1) a = NASSIGN - 1;
    toks[i] = tok_of[a];
  }
  __syncthreads();

  // staging: thread covers slot st=tid&7, sub-row sr=tid>>3 (64 rows/issue)
  const int st = tid & 7, sr = tid >> 3;
  const int scol = ((st ^ (sr & 7)) << 3);    // pre-swizzled global col (elems)
  const unsigned short* a_src[4];
#pragma unroll
  for (int i = 0; i < 4; ++i)
    a_src[i] = xb + (size_t)toks[i * 64 + sr] * HID + scol;
  const unsigned short* bg_src[2];
  const unsigned short* bu_src[2];
#pragma unroll
  for (int i = 0; i < 2; ++i) {
    bg_src[i] = WgT + ((size_t)e * FFD + n0 + i * 64 + sr) * HID + scol;
    bu_src[i] = WuT + ((size_t)e * FFD + n0 + i * 64 + sr) * HID + scol;
  }

  auto STAGE = [&](int kt) {
    const int b = kt & 1, k0 = kt * BK;
#pragma unroll
    for (int i = 0; i < 4; ++i) gload16(a_src[i] + k0, &As[b][i * 4096 + tid * 8]);
#pragma unroll
    for (int i = 0; i < 2; ++i) {
      gload16(bg_src[i] + k0, &Bgs[b][i * 4096 + tid * 8]);
      gload16(bu_src[i] + k0, &Bus[b][i * 4096 + tid * 8]);
    }
  };

  // read-side: frag for (row R, kstep ks): elems R*64 + ((ks*4+lq)^(lr&7))*8
  const int lr = lane & 15, lq = lane >> 4;
  const int sA0 = (((0 * 4 + lq) ^ (lr & 7)) << 3);
  const int sA1 = (((1 * 4 + lq) ^ (lr & 7)) << 3);
  const int wm = w >> 2, wn = w & 3;          // 2M x 4N waves

  f32x4 accg[8][2] = {};
  f32x4 accu[8][2] = {};

  STAGE(0);

  const int NT = HID / BK;   // 16
#pragma unroll 1
  for (int kt = 0; kt < NT; ++kt) {
    const int b = kt & 1;
    if (kt + 1 < NT) {
      STAGE(kt + 1);
      asm volatile("s_waitcnt vmcnt(8)" ::: "memory");   // kt's 8 landed
    } else {
      asm volatile("s_waitcnt vmcnt(0)" ::: "memory");
    }
    __builtin_amdgcn_s_barrier();

    const unsigned short* Ab = As[b];
    const unsigned short* Gb = Bgs[b];
    const unsigned short* Ub = Bus[b];
    bf16x8 af[4], bg[2], bu[2];

#pragma unroll
    for (int ks = 0; ks < 2; ++ks) {
      const int sA = ks ? sA1 : sA0;
      // ---- phase (mh=0, ks): load af(mh0) + bg + bu, 16 MFMA
#pragma unroll
      for (int m = 0; m < 4; ++m)
        af[m] = *(const bf16x8*)(Ab + (wm * 128 + m * 16 + lr) * BK + sA);
#pragma unroll
      for (int nn = 0; nn < 2; ++nn) {
        bg[nn] = *(const bf16x8*)(Gb + (wn * 32 + nn * 16 + lr) * BK + sA);
        bu[nn] = *(const bf16x8*)(Ub + (wn * 32 + nn * 16 + lr) * BK + sA);
      }
      __builtin_amdgcn_s_barrier();
      asm volatile("s_waitcnt lgkmcnt(0)" ::: "memory");
      __builtin_amdgcn_sched_barrier(0);
      __builtin_amdgcn_s_setprio(1);
#pragma unroll
      for (int m = 0; m < 4; ++m)
#pragma unroll
        for (int nn = 0; nn < 2; ++nn) {
          accg[m][nn] = __builtin_amdgcn_mfma_f32_16x16x32_bf16(af[m], bg[nn], accg[m][nn], 0, 0, 0);
          accu[m][nn] = __builtin_amdgcn_mfma_f32_16x16x32_bf16(af[m], bu[nn], accu[m][nn], 0, 0, 0);
        }
      __builtin_amdgcn_s_setprio(0);
      __builtin_amdgcn_s_barrier();
      // ---- phase (mh=1, ks): load af(mh1), 16 MFMA (bg/bu reused)
#pragma unroll
      for (int m = 0; m < 4; ++m)
        af[m] = *(const bf16x8*)(Ab + (wm * 128 + 64 + m * 16 + lr) * BK + sA);
      __builtin_amdgcn_s_barrier();
      asm volatile("s_waitcnt lgkmcnt(0)" ::: "memory");
      __builtin_amdgcn_sched_barrier(0);
      __builtin_amdgcn_s_setprio(1);
#pragma unroll
      for (int m = 0; m < 4; ++m)
#pragma unroll
        for (int nn = 0; nn < 2; ++nn) {
          accg[4 + m][nn] = __builtin_amdgcn_mfma_f32_16x16x32_bf16(af[m], bg[nn], accg[4 + m][nn], 0, 0, 0);
          accu[4 + m][nn] = __builtin_amdgcn_mfma_f32_16x16x32_bf16(af[m], bu[nn], accu[4 + m][nn], 0, 0, 0);
        }
      __builtin_amdgcn_s_setprio(0);
      __builtin_amdgcn_s_barrier();
    }
  }

  const int crb = (lane >> 4) * 4, cc = lane & 15;
#pragma unroll
  for (int m = 0; m < 8; ++m)
#pragma unroll
    for (int nn = 0; nn < 2; ++nn)
#pragma unroll
      for (int r = 0; r < 4; ++r) {
        int lrow = wm * 128 + m * 16 + crb + r;
        int grow = mblk * UBM + lrow;
        if (grow < cnt) {
          size_t a = (size_t)off + grow;
          float g = accg[m][nn][r];
          float u = accu[m][nn][r];
          float sg = g / (1.0f + __expf(-g));   // silu
          hbuf[a * FFD + (n0 + wn * 32 + nn * 16 + cc)] = f2bf(sg * u);
        }
      }
}

// ---- down: BM=256 x BN=256 ----
#define DBM 256
#define DBN 256

__global__ __launch_bounds__(512, 1) void moe_down_kernel(
    const unsigned short* __restrict__ hb,    // [A][F] bf16
    const unsigned short* __restrict__ WdT,   // [E][H][F] bf16
    const int* __restrict__ counts, const int* __restrict__ offsets,
    float* __restrict__ ypart)                // [A][H] fp32
{
  const int e = blockIdx.x & 7;               // expert <-> XCD affinity
  const int mblk = blockIdx.x >> 3;
  const int cnt = counts[e];
  if (mblk * DBM >= cnt) return;
  const int off = offsets[e];
  const int n0 = blockIdx.y * DBN;

  __shared__ __align__(16) unsigned short As[2][DBM * BK];   // 64 KiB
  __shared__ __align__(16) unsigned short Bs[2][DBN * BK];   // 64 KiB

  const int tid = threadIdx.x;
  const int lane = tid & 63;
  const int w = tid >> 6;

  const int st = tid & 7, sr = tid >> 3;
  const int scol = ((st ^ (sr & 7)) << 3);
  const unsigned short* a_src[4];
  const unsigned short* b_src[4];
#pragma unroll
  for (int i = 0; i < 4; ++i) {
    int ar = off + mblk * DBM + i * 64 + sr;
    if (ar > NASSIGN - 1) ar = NASSIGN - 1;
    a_src[i] = hb + (size_t)ar * FFD + scol;
    b_src[i] = WdT + ((size_t)e * HID + n0 + i * 64 + sr) * FFD + scol;
  }

  auto STAGE = [&](int kt) {
    const int b = kt & 1, k0 = kt * BK;
#pragma unroll
    for (int i = 0; i < 4; ++i) {
      gload16(a_src[i] + k0, &As[b][i * 4096 + tid * 8]);
      gload16(b_src[i] + k0, &Bs[b][i * 4096 + tid * 8]);
    }
  };

  const int lr = lane & 15, lq = lane >> 4;
  const int sA0 = (((0 * 4 + lq) ^ (lr & 7)) << 3);
  const int sA1 = (((1 * 4 + lq) ^ (lr & 7)) << 3);
  const int wm = w >> 2, wn = w & 3;

  f32x4 acc[8][4] = {};

  STAGE(0);

  const int NT = FFD / BK;   // 64
#pragma unroll 1
  for (int kt = 0; kt < NT; ++kt) {
    const int b = kt & 1;
    if (kt + 1 < NT) {
      STAGE(kt + 1);
      asm volatile("s_waitcnt vmcnt(8)" ::: "memory");
    } else {
      asm volatile("s_waitcnt vmcnt(0)" ::: "memory");
    }
    __builtin_amdgcn_s_barrier();

    const unsigned short* Ab = As[b];
    const unsigned short* Bb = Bs[b];
    bf16x8 af[4], bf_[4];

#pragma unroll
    for (int ks = 0; ks < 2; ++ks) {
      const int sA = ks ? sA1 : sA0;
      // ---- phase (mh=0, ks): af(mh0) + bf, 16 MFMA
#pragma unroll
      for (int m = 0; m < 4; ++m)
        af[m] = *(const bf16x8*)(Ab + (wm * 128 + m * 16 + lr) * BK + sA);
#pragma unroll
      for (int n = 0; n < 4; ++n)
        bf_[n] = *(const bf16x8*)(Bb + (wn * 64 + n * 16 + lr) * BK + sA);
      __builtin_amdgcn_s_barrier();
      asm volatile("s_waitcnt lgkmcnt(0)" ::: "memory");
      __builtin_amdgcn_sched_barrier(0);
      __builtin_amdgcn_s_setprio(1);
#pragma unroll
      for (int m = 0; m < 4; ++m)
#pragma unroll
        for (int n = 0; n < 4; ++n)
          acc[m][n] = __builtin_amdgcn_mfma_f32_16x16x32_bf16(af[m], bf_[n], acc[m][n], 0, 0, 0);
      __builtin_amdgcn_s_setprio(0);
      __builtin_amdgcn_s_barrier();
      // ---- phase (mh=1, ks): af(mh1), 16 MFMA (bf reused)
#pragma unroll
      for (int m = 0; m < 4; ++m)
        af[m] = *(const bf16x8*)(Ab + (wm * 128 + 64 + m * 16 + lr) * BK + sA);
      __builtin_amdgcn_s_barrier();
      asm volatile("s_waitcnt lgkmcnt(0)" ::: "memory");
      __builtin_amdgcn_sched_barrier(0);
      __builtin_amdgcn_s_setprio(1);
#pragma unroll
      for (int m = 0; m < 4; ++m)
#pragma unroll
        for (int n = 0; n < 4; ++n)
          acc[4 + m][n] = __builtin_amdgcn_mfma_f32_16x16x32_bf16(af[m], bf_[n], acc[4 + m][n], 0, 0, 0);
      __builtin_amdgcn_s_setprio(0);
      __builtin_amdgcn_s_barrier();
    }
  }

  const int crb = (lane >> 4) * 4, cc = lane & 15;
#pragma unroll
  for (int m = 0; m < 8; ++m)
#pragma unroll
    for (int n = 0; n < 4; ++n)
#pragma unroll
      for (int r = 0; r < 4; ++r) {
        int lrow = wm * 128 + m * 16 + crb + r;
        int grow = mblk * DBM + lrow;
        if (grow < cnt)
          ypart[((size_t)off + grow) * HID + (n0 + wn * 64 + n * 16 + cc)] = acc[m][n][r];
      }
}

__global__ void combine_kernel(const float* __restrict__ ypart,
                               const int* __restrict__ asn_of,
                               const float* __restrict__ wt_of,
                               float* __restrict__ y) {
  const int t = blockIdx.x;
  const int a0 = asn_of[t * 2], a1 = asn_of[t * 2 + 1];
  const float w0 = wt_of[a0], w1 = wt_of[a1];
  const int c = threadIdx.x * 4;
  float4 p0 = *(const float4*)&ypart[(size_t)a0 * HID + c];
  float4 p1 = *(const float4*)&ypart[(size_t)a1 * HID + c];
  float4 r;
  r.x = w0 * p0.x + w1 * p1.x;
  r.y = w0 * p0.y + w1 * p1.y;
  r.z = w0 * p0.z + w1 * p1.z;
  r.w = w0 * p0.w + w1 * p1.w;
  *(float4*)&y[(size_t)t * HID + c] = r;
}

// ---------------- launch ----------------

extern "C" void kernel_launch(void* const* d_in, const int* in_sizes, int n_in,
                              void* d_out, int out_size, void* d_ws, size_t ws_size,
                              hipStream_t stream) {
  const float* x  = (const float*)d_in[0];
  const float* gw = (const float*)d_in[1];
  const float* gb = (const float*)d_in[2];
  const float* Wg = (const float*)d_in[3];
  const float* Wu = (const float*)d_in[4];
  const float* Wd = (const float*)d_in[5];
  float* out = (float*)d_out;
  float* logits = out + (size_t)TTOK * HID;

  char* ws = (char*)d_ws;
  size_t o = 0;
  auto carve = [&](size_t b) { char* p = ws + o; o += (b + 255) & ~(size_t)255; return p; };
  int*   counts  = (int*)carve(NEXP * 4);
  int*   offsets = (int*)carve(NEXP * 4);
  int*   te      = (int*)carve((size_t)TTOK * 2 * 4);
  int*   tp      = (int*)carve((size_t)TTOK * 2 * 4);
  float* tw      = (float*)carve((size_t)TTOK * 2 * 4);
  int*   tok_of  = (int*)carve((size_t)NASSIGN * 4);
  float* wt_of   = (float*)carve((size_t)NASSIGN * 4);
  int*   asn_of  = (int*)carve((size_t)TTOK * 2 * 4);
  unsigned short* xb  = (unsigned short*)carve((size_t)TTOK * HID * 2);
  unsigned short* WgT = (unsigned short*)carve((size_t)NEXP * FFD * HID * 2);
  unsigned short* WuT = (unsigned short*)carve((size_t)NEXP * FFD * HID * 2);
  unsigned short* WdT = (unsigned short*)carve((size_t)NEXP * HID * FFD * 2);
  unsigned short* hb  = (unsigned short*)carve((size_t)NASSIGN * FFD * 2);
  float* ypart        = (float*)carve((size_t)NASSIGN * HID * 4);
  (void)ws_size; (void)in_sizes; (void)n_in; (void)out_size;

  zero_counts_kernel<<<dim3(1), dim3(64), 0, stream>>>(counts);
  gate_kernel<<<dim3(TTOK / 4), dim3(256), 0, stream>>>(x, gw, gb, logits, counts, te, tp, tw);
  scatter_kernel<<<dim3(1), dim3(256), 0, stream>>>(counts, offsets, te, tp, tw, tok_of, wt_of, asn_of);
  convert_x_kernel<<<dim3((TTOK * HID) / 2048), dim3(256), 0, stream>>>(x, xb);
  transpose_cvt_kernel<<<dim3(FFD / 32, HID / 32, NEXP), dim3(32, 8), 0, stream>>>(Wg, WgT, HID, FFD);
  transpose_cvt_kernel<<<dim3(FFD / 32, HID / 32, NEXP), dim3(32, 8), 0, stream>>>(Wu, WuT, HID, FFD);
  transpose_cvt_kernel<<<dim3(HID / 32, FFD / 32, NEXP), dim3(32, 8), 0, stream>>>(Wd, WdT, FFD, HID);
  // up: grid.x = 8 experts * 32 max m-tiles (256 rows each), grid.y = 4096/128
  moe_up_kernel<<<dim3(NEXP * 32, FFD / UBN), dim3(512), 0, stream>>>(xb, WgT, WuT, counts, offsets, tok_of, hb);
  // down: grid.x = 8 * 32, grid.y = 1024/256
  moe_down_kernel<<<dim3(NEXP * 32, HID / DBN), dim3(512), 0, stream>>>(hb, WdT, counts, offsets, ypart);
  combine_kernel<<<dim3(TTOK), dim3(256), 0, stream>>>(ypart, asn_of, wt_of, out);
}

// Round 6
// 1179.662 us; speedup vs baseline: 1.1080x; 1.1080x over previous
//
#include <hip/hip_runtime.h>
#include <cstdint>

#define TTOK 8192
#define HID  1024
#define FFD  4096
#define NEXP 8
#define NASSIGN 16384   // TTOK * 2
#define MCAP 12         // max 256-row m-groups per expert (cnt<=3072 guaranteed)

typedef __attribute__((ext_vector_type(8))) short bf16x8;
typedef __attribute__((ext_vector_type(4))) float f32x4;

__device__ __forceinline__ unsigned short f2bf(float f) {
  unsigned int u = __builtin_bit_cast(unsigned int, f);
  u += 0x7FFFu + ((u >> 16) & 1u);           // RNE
  return (unsigned short)(u >> 16);
}

__device__ __forceinline__ float bf2f(unsigned short s) {
  unsigned int u = (unsigned int)s << 16;
  return __builtin_bit_cast(float, u);
}

__device__ __forceinline__ void gload16(const unsigned short* g, unsigned short* l) {
  __builtin_amdgcn_global_load_lds(
      (const __attribute__((address_space(1))) unsigned int*)g,
      (__attribute__((address_space(3))) unsigned int*)l, 16, 0, 0);
}

// ---------------- routing ----------------

__global__ void zero_counts_kernel(int* counts) {
  if (threadIdx.x < NEXP) counts[threadIdx.x] = 0;
}

__global__ void gate_kernel(const float* __restrict__ x,
                            const float* __restrict__ gw,
                            const float* __restrict__ gb,
                            float* __restrict__ logits_out,
                            int* __restrict__ counts,
                            int* __restrict__ te, int* __restrict__ tp,
                            float* __restrict__ tw) {
  const int lane = threadIdx.x & 63;
  const int wib  = threadIdx.x >> 6;
  const int t = blockIdx.x * 4 + wib;
  const float* xr = x + (size_t)t * HID;

  float acc[NEXP];
#pragma unroll
  for (int e = 0; e < NEXP; ++e) acc[e] = 0.f;

#pragma unroll
  for (int i = 0; i < HID / 64; ++i) {
    int h = lane + 64 * i;
    float xv = xr[h];
    const float* g = gw + h * NEXP;
#pragma unroll
    for (int e = 0; e < NEXP; ++e) acc[e] += xv * g[e];
  }
#pragma unroll
  for (int off = 32; off; off >>= 1)
#pragma unroll
    for (int e = 0; e < NEXP; ++e) acc[e] += __shfl_xor(acc[e], off);
#pragma unroll
  for (int e = 0; e < NEXP; ++e) acc[e] += gb[e];

  if (lane < NEXP) logits_out[(size_t)t * NEXP + lane] = acc[lane];

  if (lane == 0) {
    int e0 = 0; float v0 = acc[0];
#pragma unroll
    for (int e = 1; e < NEXP; ++e) if (acc[e] > v0) { v0 = acc[e]; e0 = e; }
    int e1 = -1; float v1 = -3.4e38f;
#pragma unroll
    for (int e = 0; e < NEXP; ++e) if (e != e0 && acc[e] > v1) { v1 = acc[e]; e1 = e; }
    float s = __expf(v1 - v0);         // v1 <= v0
    float w0 = 1.f / (1.f + s);
    float w1 = s * w0;
    int p0 = atomicAdd(&counts[e0], 1);
    int p1 = atomicAdd(&counts[e1], 1);
    te[t * 2] = e0; te[t * 2 + 1] = e1;
    tp[t * 2] = p0; tp[t * 2 + 1] = p1;
    tw[t * 2] = w0; tw[t * 2 + 1] = w1;
  }
}

__global__ void scatter_kernel(const int* __restrict__ counts, int* __restrict__ offsets,
                               const int* __restrict__ te, const int* __restrict__ tp,
                               const float* __restrict__ tw,
                               int* __restrict__ tok_of, float* __restrict__ wt_of,
                               int* __restrict__ asn_of) {
  __shared__ int offs[NEXP];
  if (threadIdx.x == 0) {
    int run = 0;
    for (int e = 0; e < NEXP; ++e) { offs[e] = run; offsets[e] = run; run += counts[e]; }
  }
  __syncthreads();
  for (int t = threadIdx.x; t < TTOK; t += blockDim.x) {
#pragma unroll
    for (int j = 0; j < 2; ++j) {
      int e = te[t * 2 + j];
      int a = offs[e] + tp[t * 2 + j];
      tok_of[a] = t;
      wt_of[a] = tw[t * 2 + j];
      asn_of[t * 2 + j] = a;
    }
  }
}

// ---------------- dtype prep ----------------

__global__ void convert_x_kernel(const float* __restrict__ x, unsigned short* __restrict__ xb) {
  size_t i = ((size_t)blockIdx.x * 256 + threadIdx.x) * 8;
  float4 a = *(const float4*)(x + i);
  float4 b = *(const float4*)(x + i + 4);
  union { unsigned short us[8]; uint4 v; } u;
  u.us[0] = f2bf(a.x); u.us[1] = f2bf(a.y); u.us[2] = f2bf(a.z); u.us[3] = f2bf(a.w);
  u.us[4] = f2bf(b.x); u.us[5] = f2bf(b.y); u.us[6] = f2bf(b.z); u.us[7] = f2bf(b.w);
  *(uint4*)(xb + i) = u.v;
}

// src [z][R][C] fp32 -> dst [z][C][R] bf16
__global__ void transpose_cvt_kernel(const float* __restrict__ src,
                                     unsigned short* __restrict__ dst, int R, int C) {
  __shared__ float tile[32][33];
  const int r0 = blockIdx.y * 32, c0 = blockIdx.x * 32;
  const size_t base = (size_t)blockIdx.z * R * C;
  src += base; dst += base;
#pragma unroll
  for (int i = threadIdx.y; i < 32; i += 8)
    tile[i][threadIdx.x] = src[(size_t)(r0 + i) * C + c0 + threadIdx.x];
  __syncthreads();
#pragma unroll
  for (int i = threadIdx.y; i < 32; i += 8)
    dst[(size_t)(c0 + i) * R + r0 + threadIdx.x] = f2bf(tile[threadIdx.x][i]);
}

// ---------------- expert GEMMs ----------------
// m97-style free-scheduled interior at scale: BK=64, double-buffered LDS,
// ONE counted vmcnt + TWO barriers per K-tile; NO lgkmcnt asm, NO
// sched_barrier, NO setprio (m141/m190: these hurt/are-null on this
// structure). Conflict-free LDS via source-side slot swizzle
// col=(slot^(row&7))*8 staged linearly, read with same XOR (rule #21).
// e = blockIdx.x & 7 pins expert e to XCD e (grid.x % 8 == 0 so the
// linearized workgroup id preserves x&7 round-robin).

#define BK 64

// ---- up: BM=256 rows x BN=128 f-cols, g and u fused, 512 thr / 8 waves ----
#define UBM 256
#define UBN 128

__global__ __launch_bounds__(512, 1) void moe_up_kernel(
    const unsigned short* __restrict__ xb,    // [T][H] bf16
    const unsigned short* __restrict__ WgT,   // [E][F][H] bf16
    const unsigned short* __restrict__ WuT,   // [E][F][H] bf16
    const int* __restrict__ counts, const int* __restrict__ offsets,
    const int* __restrict__ tok_of,
    unsigned short* __restrict__ hbuf)        // [A][F] bf16
{
  const int e = blockIdx.x & 7;               // expert <-> XCD affinity
  const int mblk = blockIdx.x >> 3;           // 0..MCAP-1
  const int cnt = counts[e];
  if (mblk * UBM >= cnt) return;
  const int off = offsets[e];
  const int n0 = blockIdx.y * UBN;

  __shared__ __align__(16) unsigned short As[2][UBM * BK];    // 64 KiB
  __shared__ __align__(16) unsigned short Bgs[2][UBN * BK];   // 32 KiB
  __shared__ __align__(16) unsigned short Bus[2][UBN * BK];   // 32 KiB
  __shared__ int toks[UBM];

  const int tid = threadIdx.x;
  const int lane = tid & 63;
  const int w = tid >> 6;

  for (int i = tid; i < UBM; i += 512) {
    int a = off + mblk * UBM + i;
    if (a > NASSIGN - 1) a = NASSIGN - 1;
    toks[i] = tok_of[a];
  }
  __syncthreads();

  // staging: thread = (slot st 0..7, sub-row sr 0..63); 16B per issue
  const int st = tid & 7, sr = tid >> 3;
  const int scol = ((st ^ (sr & 7)) << 3);    // pre-swizzled global col
  const unsigned short* a_src[4];
#pragma unroll
  for (int i = 0; i < 4; ++i)
    a_src[i] = xb + (size_t)toks[i * 64 + sr] * HID + scol;
  const unsigned short* bg_src[2];
  const unsigned short* bu_src[2];
#pragma unroll
  for (int i = 0; i < 2; ++i) {
    bg_src[i] = WgT + ((size_t)e * FFD + n0 + i * 64 + sr) * HID + scol;
    bu_src[i] = WuT + ((size_t)e * FFD + n0 + i * 64 + sr) * HID + scol;
  }

  auto STAGE = [&](int kt) {                  // 8 gloads / thread
    const int b = kt & 1, k0 = kt * BK;
#pragma unroll
    for (int i = 0; i < 4; ++i) gload16(a_src[i] + k0, &As[b][i * 4096 + tid * 8]);
#pragma unroll
    for (int i = 0; i < 2; ++i) {
      gload16(bg_src[i] + k0, &Bgs[b][i * 4096 + tid * 8]);
      gload16(bu_src[i] + k0, &Bus[b][i * 4096 + tid * 8]);
    }
  };

  // read-side swizzle: slot = ks*4+lq, XOR row&7 (= lr&7; 16|row offsets)
  const int lr = lane & 15, lq = lane >> 4;
  const int sK0 = (((0 * 4 + lq) ^ (lr & 7)) << 3);
  const int sK1 = (((1 * 4 + lq) ^ (lr & 7)) << 3);
  const int wm = w >> 2, wn = w & 3;          // 2M x 4N waves: tile 128 x 32

  f32x4 accg[8][2] = {};
  f32x4 accu[8][2] = {};

  STAGE(0);

  const int NT = HID / BK;   // 16
#pragma unroll 1
  for (int kt = 0; kt < NT; ++kt) {
    const int b = kt & 1;
    if (kt + 1 < NT) {
      STAGE(kt + 1);
      asm volatile("s_waitcnt vmcnt(8)" ::: "memory");   // kt's 8 landed
    } else {
      asm volatile("s_waitcnt vmcnt(0)" ::: "memory");
    }
    __builtin_amdgcn_s_barrier();             // buf b ready

    const unsigned short* Ab = As[b];
    const unsigned short* Gb = Bgs[b];
    const unsigned short* Ub = Bus[b];

#pragma unroll
    for (int ks = 0; ks < 2; ++ks) {
      const int sK = ks ? sK1 : sK0;
      bf16x8 bg[2], bu[2];
#pragma unroll
      for (int nn = 0; nn < 2; ++nn) {
        bg[nn] = *(const bf16x8*)(Gb + (wn * 32 + nn * 16 + lr) * BK + sK);
        bu[nn] = *(const bf16x8*)(Ub + (wn * 32 + nn * 16 + lr) * BK + sK);
      }
#pragma unroll
      for (int mh = 0; mh < 2; ++mh) {
        bf16x8 af[4];
#pragma unroll
        for (int m = 0; m < 4; ++m)
          af[m] = *(const bf16x8*)(Ab + (wm * 128 + mh * 64 + m * 16 + lr) * BK + sK);
#pragma unroll
        for (int m = 0; m < 4; ++m)
#pragma unroll
          for (int nn = 0; nn < 2; ++nn) {
            accg[mh * 4 + m][nn] = __builtin_amdgcn_mfma_f32_16x16x32_bf16(af[m], bg[nn], accg[mh * 4 + m][nn], 0, 0, 0);
            accu[mh * 4 + m][nn] = __builtin_amdgcn_mfma_f32_16x16x32_bf16(af[m], bu[nn], accu[mh * 4 + m][nn], 0, 0, 0);
          }
      }
    }
    __builtin_amdgcn_s_barrier();             // reads of b retired before overwrite
  }

  const int crb = (lane >> 4) * 4, cc = lane & 15;
#pragma unroll
  for (int m = 0; m < 8; ++m)
#pragma unroll
    for (int nn = 0; nn < 2; ++nn)
#pragma unroll
      for (int r = 0; r < 4; ++r) {
        int lrow = wm * 128 + (m >> 2) * 64 + (m & 3) * 16 + crb + r;
        int grow = mblk * UBM + lrow;
        if (grow < cnt) {
          size_t a = (size_t)off + grow;
          float g = accg[m][nn][r];
          float u = accu[m][nn][r];
          float sg = g / (1.0f + __expf(-g));   // silu
          hbuf[a * FFD + (n0 + wn * 32 + nn * 16 + cc)] = f2bf(sg * u);
        }
      }
}

// ---- down: BM=256 x BN=128, 512 thr / 8 waves, bf16 ypart out ----
#define DBM 256
#define DBN 128

__global__ __launch_bounds__(512, 1) void moe_down_kernel(
    const unsigned short* __restrict__ hb,    // [A][F] bf16
    const unsigned short* __restrict__ WdT,   // [E][H][F] bf16
    const int* __restrict__ counts, const int* __restrict__ offsets,
    unsigned short* __restrict__ ypart)       // [A][H] bf16
{
  const int e = blockIdx.x & 7;               // expert <-> XCD affinity
  const int mblk = blockIdx.x >> 3;
  const int cnt = counts[e];
  if (mblk * DBM >= cnt) return;
  const int off = offsets[e];
  const int n0 = blockIdx.y * DBN;

  __shared__ __align__(16) unsigned short As[2][DBM * BK];   // 64 KiB
  __shared__ __align__(16) unsigned short Bs[2][DBN * BK];   // 32 KiB

  const int tid = threadIdx.x;
  const int lane = tid & 63;
  const int w = tid >> 6;

  const int st = tid & 7, sr = tid >> 3;
  const int scol = ((st ^ (sr & 7)) << 3);
  const unsigned short* a_src[4];
#pragma unroll
  for (int i = 0; i < 4; ++i) {
    int ar = off + mblk * DBM + i * 64 + sr;
    if (ar > NASSIGN - 1) ar = NASSIGN - 1;
    a_src[i] = hb + (size_t)ar * FFD + scol;
  }
  const unsigned short* b_src[2];
#pragma unroll
  for (int i = 0; i < 2; ++i)
    b_src[i] = WdT + ((size_t)e * HID + n0 + i * 64 + sr) * FFD + scol;

  auto STAGE = [&](int kt) {                  // 6 gloads / thread
    const int b = kt & 1, k0 = kt * BK;
#pragma unroll
    for (int i = 0; i < 4; ++i) gload16(a_src[i] + k0, &As[b][i * 4096 + tid * 8]);
#pragma unroll
    for (int i = 0; i < 2; ++i) gload16(b_src[i] + k0, &Bs[b][i * 4096 + tid * 8]);
  };

  const int lr = lane & 15, lq = lane >> 4;
  const int sK0 = (((0 * 4 + lq) ^ (lr & 7)) << 3);
  const int sK1 = (((1 * 4 + lq) ^ (lr & 7)) << 3);
  const int wm = w >> 2, wn = w & 3;          // wave tile 128 x 32

  f32x4 acc[8][2] = {};

  STAGE(0);

  const int NT = FFD / BK;   // 64
#pragma unroll 1
  for (int kt = 0; kt < NT; ++kt) {
    const int b = kt & 1;
    if (kt + 1 < NT) {
      STAGE(kt + 1);
      asm volatile("s_waitcnt vmcnt(6)" ::: "memory");
    } else {
      asm volatile("s_waitcnt vmcnt(0)" ::: "memory");
    }
    __builtin_amdgcn_s_barrier();

    const unsigned short* Ab = As[b];
    const unsigned short* Bb = Bs[b];

#pragma unroll
    for (int ks = 0; ks < 2; ++ks) {
      const int sK = ks ? sK1 : sK0;
      bf16x8 bf_[2];
#pragma unroll
      for (int nn = 0; nn < 2; ++nn)
        bf_[nn] = *(const bf16x8*)(Bb + (wn * 32 + nn * 16 + lr) * BK + sK);
#pragma unroll
      for (int mh = 0; mh < 2; ++mh) {
        bf16x8 af[4];
#pragma unroll
        for (int m = 0; m < 4; ++m)
          af[m] = *(const bf16x8*)(Ab + (wm * 128 + mh * 64 + m * 16 + lr) * BK + sK);
#pragma unroll
        for (int m = 0; m < 4; ++m)
#pragma unroll
          for (int nn = 0; nn < 2; ++nn)
            acc[mh * 4 + m][nn] = __builtin_amdgcn_mfma_f32_16x16x32_bf16(af[m], bf_[nn], acc[mh * 4 + m][nn], 0, 0, 0);
      }
    }
    __builtin_amdgcn_s_barrier();
  }

  const int crb = (lane >> 4) * 4, cc = lane & 15;
#pragma unroll
  for (int m = 0; m < 8; ++m)
#pragma unroll
    for (int nn = 0; nn < 2; ++nn)
#pragma unroll
      for (int r = 0; r < 4; ++r) {
        int lrow = wm * 128 + (m >> 2) * 64 + (m & 3) * 16 + crb + r;
        int grow = mblk * DBM + lrow;
        if (grow < cnt)
          ypart[((size_t)off + grow) * HID + (n0 + wn * 32 + nn * 16 + cc)] = f2bf(acc[m][nn][r]);
      }
}

__global__ void combine_kernel(const unsigned short* __restrict__ ypart,  // [A][H] bf16
                               const int* __restrict__ asn_of,
                               const float* __restrict__ wt_of,
                               float* __restrict__ y) {
  const int t = blockIdx.x;
  const int a0 = asn_of[t * 2], a1 = asn_of[t * 2 + 1];
  const float w0 = wt_of[a0], w1 = wt_of[a1];
  const int c = threadIdx.x * 4;
  ushort4 p0 = *(const ushort4*)&ypart[(size_t)a0 * HID + c];
  ushort4 p1 = *(const ushort4*)&ypart[(size_t)a1 * HID + c];
  float4 r;
  r.x = w0 * bf2f(p0.x) + w1 * bf2f(p1.x);
  r.y = w0 * bf2f(p0.y) + w1 * bf2f(p1.y);
  r.z = w0 * bf2f(p0.z) + w1 * bf2f(p1.z);
  r.w = w0 * bf2f(p0.w) + w1 * bf2f(p1.w);
  *(float4*)&y[(size_t)t * HID + c] = r;
}

// ---------------- launch ----------------

extern "C" void kernel_launch(void* const* d_in, const int* in_sizes, int n_in,
                              void* d_out, int out_size, void* d_ws, size_t ws_size,
                              hipStream_t stream) {
  const float* x  = (const float*)d_in[0];
  const float* gw = (const float*)d_in[1];
  const float* gb = (const float*)d_in[2];
  const float* Wg = (const float*)d_in[3];
  const float* Wu = (const float*)d_in[4];
  const float* Wd = (const float*)d_in[5];
  float* out = (float*)d_out;
  float* logits = out + (size_t)TTOK * HID;

  char* ws = (char*)d_ws;
  size_t o = 0;
  auto carve = [&](size_t b) { char* p = ws + o; o += (b + 255) & ~(size_t)255; return p; };
  int*   counts  = (int*)carve(NEXP * 4);
  int*   offsets = (int*)carve(NEXP * 4);
  int*   te      = (int*)carve((size_t)TTOK * 2 * 4);
  int*   tp      = (int*)carve((size_t)TTOK * 2 * 4);
  float* tw      = (float*)carve((size_t)TTOK * 2 * 4);
  int*   tok_of  = (int*)carve((size_t)NASSIGN * 4);
  float* wt_of   = (float*)carve((size_t)NASSIGN * 4);
  int*   asn_of  = (int*)carve((size_t)TTOK * 2 * 4);
  unsigned short* xb  = (unsigned short*)carve((size_t)TTOK * HID * 2);
  unsigned short* WgT = (unsigned short*)carve((size_t)NEXP * FFD * HID * 2);
  unsigned short* WuT = (unsigned short*)carve((size_t)NEXP * FFD * HID * 2);
  unsigned short* WdT = (unsigned short*)carve((size_t)NEXP * HID * FFD * 2);
  unsigned short* hb  = (unsigned short*)carve((size_t)NASSIGN * FFD * 2);
  unsigned short* ypart = (unsigned short*)carve((size_t)NASSIGN * HID * 2);
  (void)ws_size; (void)in_sizes; (void)n_in; (void)out_size;

  zero_counts_kernel<<<dim3(1), dim3(64), 0, stream>>>(counts);
  gate_kernel<<<dim3(TTOK / 4), dim3(256), 0, stream>>>(x, gw, gb, logits, counts, te, tp, tw);
  scatter_kernel<<<dim3(1), dim3(256), 0, stream>>>(counts, offsets, te, tp, tw, tok_of, wt_of, asn_of);
  convert_x_kernel<<<dim3((TTOK * HID) / 2048), dim3(256), 0, stream>>>(x, xb);
  transpose_cvt_kernel<<<dim3(FFD / 32, HID / 32, NEXP), dim3(32, 8), 0, stream>>>(Wg, WgT, HID, FFD);
  transpose_cvt_kernel<<<dim3(FFD / 32, HID / 32, NEXP), dim3(32, 8), 0, stream>>>(Wu, WuT, HID, FFD);
  transpose_cvt_kernel<<<dim3(HID / 32, FFD / 32, NEXP), dim3(32, 8), 0, stream>>>(Wd, WdT, FFD, HID);
  // grid.x = 8 experts * MCAP m-groups (x%8 = expert = XCD; 96 % 8 == 0)
  moe_up_kernel<<<dim3(NEXP * MCAP, FFD / UBN), dim3(512), 0, stream>>>(xb, WgT, WuT, counts, offsets, tok_of, hb);
  moe_down_kernel<<<dim3(NEXP * MCAP, HID / DBN), dim3(512), 0, stream>>>(hb, WdT, counts, offsets, ypart);
  combine_kernel<<<dim3(TTOK), dim3(256), 0, stream>>>(ypart, asn_of, wt_of, out);
}

// Round 7
// 970.738 us; speedup vs baseline: 1.3464x; 1.2152x over previous
//
#include <hip/hip_runtime.h>
#include <cstdint>

#define TTOK 8192
#define HID  1024
#define FFD  4096
#define NEXP 8
#define NASSIGN 16384   // TTOK * 2
#define MAXMB 24        // max 128-row m-tiles/expert; r5/r6 passing proves cnt<=3072

typedef __attribute__((ext_vector_type(8))) short bf16x8;
typedef __attribute__((ext_vector_type(4))) float f32x4;

__device__ __forceinline__ unsigned short f2bf(float f) {
  unsigned int u = __builtin_bit_cast(unsigned int, f);
  u += 0x7FFFu + ((u >> 16) & 1u);           // RNE
  return (unsigned short)(u >> 16);
}

__device__ __forceinline__ float bf2f(unsigned short s) {
  unsigned int u = (unsigned int)s << 16;
  return __builtin_bit_cast(float, u);
}

__device__ __forceinline__ void gload16(const unsigned short* g, unsigned short* l) {
  __builtin_amdgcn_global_load_lds(
      (const __attribute__((address_space(1))) unsigned int*)g,
      (__attribute__((address_space(3))) unsigned int*)l, 16, 0, 0);
}

// ---------------- routing ----------------

__global__ void zero_counts_kernel(int* counts) {
  if (threadIdx.x < NEXP) counts[threadIdx.x] = 0;
}

__global__ void gate_kernel(const float* __restrict__ x,
                            const float* __restrict__ gw,
                            const float* __restrict__ gb,
                            float* __restrict__ logits_out,
                            int* __restrict__ counts,
                            int* __restrict__ te, int* __restrict__ tp,
                            float* __restrict__ tw) {
  const int lane = threadIdx.x & 63;
  const int wib  = threadIdx.x >> 6;
  const int t = blockIdx.x * 4 + wib;
  const float* xr = x + (size_t)t * HID;

  float acc[NEXP];
#pragma unroll
  for (int e = 0; e < NEXP; ++e) acc[e] = 0.f;

#pragma unroll
  for (int i = 0; i < HID / 64; ++i) {
    int h = lane + 64 * i;
    float xv = xr[h];
    const float* g = gw + h * NEXP;
#pragma unroll
    for (int e = 0; e < NEXP; ++e) acc[e] += xv * g[e];
  }
#pragma unroll
  for (int off = 32; off; off >>= 1)
#pragma unroll
    for (int e = 0; e < NEXP; ++e) acc[e] += __shfl_xor(acc[e], off);
#pragma unroll
  for (int e = 0; e < NEXP; ++e) acc[e] += gb[e];

  if (lane < NEXP) logits_out[(size_t)t * NEXP + lane] = acc[lane];

  if (lane == 0) {
    int e0 = 0; float v0 = acc[0];
#pragma unroll
    for (int e = 1; e < NEXP; ++e) if (acc[e] > v0) { v0 = acc[e]; e0 = e; }
    int e1 = -1; float v1 = -3.4e38f;
#pragma unroll
    for (int e = 0; e < NEXP; ++e) if (e != e0 && acc[e] > v1) { v1 = acc[e]; e1 = e; }
    float s = __expf(v1 - v0);         // v1 <= v0
    float w0 = 1.f / (1.f + s);
    float w1 = s * w0;
    int p0 = atomicAdd(&counts[e0], 1);
    int p1 = atomicAdd(&counts[e1], 1);
    te[t * 2] = e0; te[t * 2 + 1] = e1;
    tp[t * 2] = p0; tp[t * 2 + 1] = p1;
    tw[t * 2] = w0; tw[t * 2 + 1] = w1;
  }
}

__global__ void scatter_kernel(const int* __restrict__ counts, int* __restrict__ offsets,
                               const int* __restrict__ te, const int* __restrict__ tp,
                               const float* __restrict__ tw,
                               int* __restrict__ tok_of, float* __restrict__ wt_of,
                               int* __restrict__ asn_of) {
  __shared__ int offs[NEXP];
  if (threadIdx.x == 0) {
    int run = 0;
    for (int e = 0; e < NEXP; ++e) { offs[e] = run; offsets[e] = run; run += counts[e]; }
  }
  __syncthreads();
  for (int t = threadIdx.x; t < TTOK; t += blockDim.x) {
#pragma unroll
    for (int j = 0; j < 2; ++j) {
      int e = te[t * 2 + j];
      int a = offs[e] + tp[t * 2 + j];
      tok_of[a] = t;
      wt_of[a] = tw[t * 2 + j];
      asn_of[t * 2 + j] = a;
    }
  }
}

// ---------------- dtype prep ----------------

__global__ void convert_x_kernel(const float* __restrict__ x, unsigned short* __restrict__ xb) {
  size_t i = ((size_t)blockIdx.x * 256 + threadIdx.x) * 8;
  float4 a = *(const float4*)(x + i);
  float4 b = *(const float4*)(x + i + 4);
  union { unsigned short us[8]; uint4 v; } u;
  u.us[0] = f2bf(a.x); u.us[1] = f2bf(a.y); u.us[2] = f2bf(a.z); u.us[3] = f2bf(a.w);
  u.us[4] = f2bf(b.x); u.us[5] = f2bf(b.y); u.us[6] = f2bf(b.z); u.us[7] = f2bf(b.w);
  *(uint4*)(xb + i) = u.v;
}

// src [z][R][C] fp32 -> dst [z][C][R] bf16; 64x64 tile, float4 in / ushort4 out
__global__ void transpose_cvt_kernel(const float* __restrict__ src,
                                     unsigned short* __restrict__ dst, int R, int C) {
  __shared__ float tile[64][65];
  const int r0 = blockIdx.y * 64, c0 = blockIdx.x * 64;
  const size_t base = (size_t)blockIdx.z * (size_t)R * C;
  src += base; dst += base;
  const int tid = threadIdx.x;
  {
    const int c4 = (tid & 15) * 4, rr = tid >> 4;
#pragma unroll
    for (int i = 0; i < 4; ++i) {
      int row = rr + i * 16;
      float4 v = *(const float4*)&src[(size_t)(r0 + row) * C + c0 + c4];
      tile[row][c4 + 0] = v.x; tile[row][c4 + 1] = v.y;
      tile[row][c4 + 2] = v.z; tile[row][c4 + 3] = v.w;
    }
  }
  __syncthreads();
  {
    const int r4 = (tid & 15) * 4, cc = tid >> 4;
#pragma unroll
    for (int i = 0; i < 4; ++i) {
      int c = cc + i * 16;
      ushort4 o;
      o.x = f2bf(tile[r4 + 0][c]);
      o.y = f2bf(tile[r4 + 1][c]);
      o.z = f2bf(tile[r4 + 2][c]);
      o.w = f2bf(tile[r4 + 3][c]);
      *(ushort4*)&dst[(size_t)(c0 + c) * R + r0 + r4] = o;
    }
  }
}

// ---------------- expert GEMMs ----------------
// Round-2 proven structure: 128x128 tile, BK=32, 4 waves (2x2), double-buffered
// LDS, 2-phase pipeline with counted vmcnt. e = blockIdx.x & 7 pins expert e
// to XCD e (consecutive blockIdx round-robin XCDs -> weight panels stay in
// one XCD's L2; r3 measured 8x weight over-fetch without this).

__global__ __launch_bounds__(256, 2) void moe_up_kernel(
    const unsigned short* __restrict__ xb,    // [T][H] bf16
    const unsigned short* __restrict__ WgT,   // [E][F][H] bf16
    const unsigned short* __restrict__ WuT,   // [E][F][H] bf16
    const int* __restrict__ counts, const int* __restrict__ offsets,
    const int* __restrict__ tok_of,
    unsigned short* __restrict__ hbuf)        // [A][F] bf16
{
  const int e = blockIdx.x & 7;
  const int mblk = blockIdx.x >> 3;
  const int cnt = counts[e];
  if (mblk * 128 >= cnt) return;
  const int off = offsets[e];
  const int n0 = blockIdx.y * 128;

  __shared__ __align__(16) unsigned short As[2][128 * 32];
  __shared__ __align__(16) unsigned short Bgs[2][128 * 32];
  __shared__ __align__(16) unsigned short Bus[2][128 * 32];
  __shared__ int toks[128];

  const int tid = threadIdx.x;
  const int lane = tid & 63;
  const int w = tid >> 6;

  if (tid < 128) {
    int a = off + mblk * 128 + tid;
    if (a > NASSIGN - 1) a = NASSIGN - 1;
    toks[tid] = tok_of[a];
  }
  __syncthreads();

  const unsigned short* asrc[2];
  const unsigned short* bgsrc[2];
  const unsigned short* busrc[2];
#pragma unroll
  for (int j = 0; j < 2; ++j) {
    int rrow = w * 32 + j * 16 + (lane >> 2);
    int kcol = 8 * (lane & 3);
    asrc[j]  = xb  + (size_t)toks[rrow] * HID + kcol;
    bgsrc[j] = WgT + ((size_t)e * FFD + n0 + rrow) * HID + kcol;
    busrc[j] = WuT + ((size_t)e * FFD + n0 + rrow) * HID + kcol;
  }

  auto STAGE = [&](int buf, int k0) {
#pragma unroll
    for (int j = 0; j < 2; ++j) {
      gload16(asrc[j]  + k0, &As[buf][w * 1024 + j * 512]);
      gload16(bgsrc[j] + k0, &Bgs[buf][w * 1024 + j * 512]);
      gload16(busrc[j] + k0, &Bus[buf][w * 1024 + j * 512]);
    }
  };

  f32x4 accg[4][4] = {};
  f32x4 accu[4][4] = {};
  const int wr = (w >> 1) * 64, wc = (w & 1) * 64;
  const int lr = lane & 15, kg = (lane >> 4) * 8;

  STAGE(0, 0);                                 // prologue: 6 loads in flight
#pragma unroll 1
  for (int t = 0; t < HID / 32; ++t) {
    const int cur = t & 1;
    if (t + 1 < HID / 32) {
      STAGE(cur ^ 1, (t + 1) * 32);            // issue next tile (6 more loads)
      asm volatile("s_waitcnt vmcnt(6)" ::: "memory");   // tile t's 6 loads done
    } else {
      asm volatile("s_waitcnt vmcnt(0)" ::: "memory");
    }
    __builtin_amdgcn_s_barrier();              // buf[cur] ready for all waves

    bf16x8 af[4], bgf[4], buf_[4];
#pragma unroll
    for (int m = 0; m < 4; ++m)
      af[m] = *(const bf16x8*)&As[cur][(wr + m * 16 + lr) * 32 + kg];
#pragma unroll
    for (int n = 0; n < 4; ++n) {
      bgf[n]  = *(const bf16x8*)&Bgs[cur][(wc + n * 16 + lr) * 32 + kg];
      buf_[n] = *(const bf16x8*)&Bus[cur][(wc + n * 16 + lr) * 32 + kg];
    }
#pragma unroll
    for (int m = 0; m < 4; ++m)
#pragma unroll
      for (int n = 0; n < 4; ++n) {
        accg[m][n] = __builtin_amdgcn_mfma_f32_16x16x32_bf16(af[m], bgf[n],  accg[m][n], 0, 0, 0);
        accu[m][n] = __builtin_amdgcn_mfma_f32_16x16x32_bf16(af[m], buf_[n], accu[m][n], 0, 0, 0);
      }
    __builtin_amdgcn_s_barrier();              // reads of buf[cur] done before overwrite
  }

  const int crb = (lane >> 4) * 4, cc = lane & 15;
#pragma unroll
  for (int m = 0; m < 4; ++m)
#pragma unroll
    for (int n = 0; n < 4; ++n)
#pragma unroll
      for (int r = 0; r < 4; ++r) {
        int lrow = wr + m * 16 + crb + r;
        int grow = mblk * 128 + lrow;
        if (grow < cnt) {
          size_t a = (size_t)off + grow;
          float g = accg[m][n][r];
          float u = accu[m][n][r];
          float sg = g / (1.0f + __expf(-g));   // silu
          hbuf[a * FFD + (n0 + wc + n * 16 + cc)] = f2bf(sg * u);
        }
      }
}

__global__ __launch_bounds__(256, 2) void moe_down_kernel(
    const unsigned short* __restrict__ hb,    // [A][F] bf16
    const unsigned short* __restrict__ WdT,   // [E][H][F] bf16
    const int* __restrict__ counts, const int* __restrict__ offsets,
    unsigned short* __restrict__ ypart)       // [A][H] bf16
{
  const int e = blockIdx.x & 7;
  const int mblk = blockIdx.x >> 3;
  const int cnt = counts[e];
  if (mblk * 128 >= cnt) return;
  const int off = offsets[e];
  const int n0 = blockIdx.y * 128;

  __shared__ __align__(16) unsigned short As[2][128 * 32];
  __shared__ __align__(16) unsigned short Bs[2][128 * 32];

  const int tid = threadIdx.x;
  const int lane = tid & 63;
  const int w = tid >> 6;

  const unsigned short* asrc[2];
  const unsigned short* bsrc[2];
#pragma unroll
  for (int j = 0; j < 2; ++j) {
    int rrow = w * 32 + j * 16 + (lane >> 2);
    int kcol = 8 * (lane & 3);
    int a = off + mblk * 128 + rrow;
    if (a > NASSIGN - 1) a = NASSIGN - 1;
    asrc[j] = hb + (size_t)a * FFD + kcol;
    bsrc[j] = WdT + ((size_t)e * HID + n0 + rrow) * FFD + kcol;
  }

  auto STAGE = [&](int buf, int k0) {
#pragma unroll
    for (int j = 0; j < 2; ++j) {
      gload16(asrc[j] + k0, &As[buf][w * 1024 + j * 512]);
      gload16(bsrc[j] + k0, &Bs[buf][w * 1024 + j * 512]);
    }
  };

  f32x4 acc[4][4] = {};
  const int wr = (w >> 1) * 64, wc = (w & 1) * 64;
  const int lr = lane & 15, kg = (lane >> 4) * 8;

  STAGE(0, 0);                                 // prologue: 4 loads in flight
#pragma unroll 1
  for (int t = 0; t < FFD / 32; ++t) {
    const int cur = t & 1;
    if (t + 1 < FFD / 32) {
      STAGE(cur ^ 1, (t + 1) * 32);            // +4 loads
      asm volatile("s_waitcnt vmcnt(4)" ::: "memory");   // tile t's 4 loads done
    } else {
      asm volatile("s_waitcnt vmcnt(0)" ::: "memory");
    }
    __builtin_amdgcn_s_barrier();

    bf16x8 af[4], bf_[4];
#pragma unroll
    for (int m = 0; m < 4; ++m)
      af[m] = *(const bf16x8*)&As[cur][(wr + m * 16 + lr) * 32 + kg];
#pragma unroll
    for (int n = 0; n < 4; ++n)
      bf_[n] = *(const bf16x8*)&Bs[cur][(wc + n * 16 + lr) * 32 + kg];
#pragma unroll
    for (int m = 0; m < 4; ++m)
#pragma unroll
      for (int n = 0; n < 4; ++n)
        acc[m][n] = __builtin_amdgcn_mfma_f32_16x16x32_bf16(af[m], bf_[n], acc[m][n], 0, 0, 0);
    __builtin_amdgcn_s_barrier();
  }

  const int crb = (lane >> 4) * 4, cc = lane & 15;
#pragma unroll
  for (int m = 0; m < 4; ++m)
#pragma unroll
    for (int n = 0; n < 4; ++n)
#pragma unroll
      for (int r = 0; r < 4; ++r) {
        int lrow = wr + m * 16 + crb + r;
        int grow = mblk * 128 + lrow;
        if (grow < cnt)
          ypart[((size_t)off + grow) * HID + (n0 + wc + n * 16 + cc)] = f2bf(acc[m][n][r]);
      }
}

__global__ void combine_kernel(const unsigned short* __restrict__ ypart,  // [A][H] bf16
                               const int* __restrict__ asn_of,
                               const float* __restrict__ wt_of,
                               float* __restrict__ y) {
  const int t = blockIdx.x;
  const int a0 = asn_of[t * 2], a1 = asn_of[t * 2 + 1];
  const float w0 = wt_of[a0], w1 = wt_of[a1];
  const int c = threadIdx.x * 4;
  ushort4 p0 = *(const ushort4*)&ypart[(size_t)a0 * HID + c];
  ushort4 p1 = *(const ushort4*)&ypart[(size_t)a1 * HID + c];
  float4 r;
  r.x = w0 * bf2f(p0.x) + w1 * bf2f(p1.x);
  r.y = w0 * bf2f(p0.y) + w1 * bf2f(p1.y);
  r.z = w0 * bf2f(p0.z) + w1 * bf2f(p1.z);
  r.w = w0 * bf2f(p0.w) + w1 * bf2f(p1.w);
  *(float4*)&y[(size_t)t * HID + c] = r;
}

// ---------------- launch ----------------

extern "C" void kernel_launch(void* const* d_in, const int* in_sizes, int n_in,
                              void* d_out, int out_size, void* d_ws, size_t ws_size,
                              hipStream_t stream) {
  const float* x  = (const float*)d_in[0];
  const float* gw = (const float*)d_in[1];
  const float* gb = (const float*)d_in[2];
  const float* Wg = (const float*)d_in[3];
  const float* Wu = (const float*)d_in[4];
  const float* Wd = (const float*)d_in[5];
  float* out = (float*)d_out;
  float* logits = out + (size_t)TTOK * HID;

  char* ws = (char*)d_ws;
  size_t o = 0;
  auto carve = [&](size_t b) { char* p = ws + o; o += (b + 255) & ~(size_t)255; return p; };
  int*   counts  = (int*)carve(NEXP * 4);
  int*   offsets = (int*)carve(NEXP * 4);
  int*   te      = (int*)carve((size_t)TTOK * 2 * 4);
  int*   tp      = (int*)carve((size_t)TTOK * 2 * 4);
  float* tw      = (float*)carve((size_t)TTOK * 2 * 4);
  int*   tok_of  = (int*)carve((size_t)NASSIGN * 4);
  float* wt_of   = (float*)carve((size_t)NASSIGN * 4);
  int*   asn_of  = (int*)carve((size_t)TTOK * 2 * 4);
  unsigned short* xb  = (unsigned short*)carve((size_t)TTOK * HID * 2);
  unsigned short* WgT = (unsigned short*)carve((size_t)NEXP * FFD * HID * 2);
  unsigned short* WuT = (unsigned short*)carve((size_t)NEXP * FFD * HID * 2);
  unsigned short* WdT = (unsigned short*)carve((size_t)NEXP * HID * FFD * 2);
  unsigned short* hb  = (unsigned short*)carve((size_t)NASSIGN * FFD * 2);
  unsigned short* ypart = (unsigned short*)carve((size_t)NASSIGN * HID * 2);
  (void)ws_size; (void)in_sizes; (void)n_in; (void)out_size;

  zero_counts_kernel<<<dim3(1), dim3(64), 0, stream>>>(counts);
  gate_kernel<<<dim3(TTOK / 4), dim3(256), 0, stream>>>(x, gw, gb, logits, counts, te, tp, tw);
  scatter_kernel<<<dim3(1), dim3(256), 0, stream>>>(counts, offsets, te, tp, tw, tok_of, wt_of, asn_of);
  convert_x_kernel<<<dim3((TTOK * HID) / 2048), dim3(256), 0, stream>>>(x, xb);
  transpose_cvt_kernel<<<dim3(FFD / 64, HID / 64, NEXP), dim3(256), 0, stream>>>(Wg, WgT, HID, FFD);
  transpose_cvt_kernel<<<dim3(FFD / 64, HID / 64, NEXP), dim3(256), 0, stream>>>(Wu, WuT, HID, FFD);
  transpose_cvt_kernel<<<dim3(HID / 64, FFD / 64, NEXP), dim3(256), 0, stream>>>(Wd, WdT, FFD, HID);
  // grid.x = 8 experts * MAXMB m-tiles; x%8 = expert = XCD (192 % 8 == 0)
  moe_up_kernel<<<dim3(NEXP * MAXMB, FFD / 128), dim3(256), 0, stream>>>(xb, WgT, WuT, counts, offsets, tok_of, hb);
  moe_down_kernel<<<dim3(NEXP * MAXMB, HID / 128), dim3(256), 0, stream>>>(hb, WdT, counts, offsets, ypart);
  combine_kernel<<<dim3(TTOK), dim3(256), 0, stream>>>(ypart, asn_of, wt_of, out);
}